// Round 8
// baseline (242.793 us; speedup 1.0000x reference)
//
#include <hip/hip_runtime.h>
#include <hip/hip_bf16.h>
#include <math.h>

#define D_DIM 1024
#define TOKB  32            // tokens per block
#define NCHW  8             // chunks per wave (split-K x 4, chunk = 32 k)
// Wp layout (ushort bf16 bits): [ks 32][fb 12][pl 2][lane 64][j 8]
//   element (lane,j): k = ks*32 + (lane>>4)*8 + j ; f = fb*16 + (lane&15)
//   frag stride = 512 ushorts (1 KB); per-ks stride = 12*2*512 = 12288 ushorts

typedef short  bf16x8 __attribute__((ext_vector_type(8)));
typedef float  f32x4  __attribute__((ext_vector_type(4)));

__device__ __forceinline__ ushort f2bf(float f) {      // RTNE fp32 -> bf16 bits
  uint u = __float_as_uint(f);
  return (ushort)((u + 0x7fffu + ((u >> 16) & 1u)) >> 16);
}
__device__ __forceinline__ float bf2f(ushort h) {
  return __uint_as_float(((uint)h) << 16);
}
__device__ __forceinline__ float sigm(float v) {
  return 1.f / (1.f + expf(-v));
}
// RTNE hi/lo split via HW pack-converter: hi = cvt_pk_bf16(v) (RTNE),
// lo = RTNE(v - hi). Same numerics as rounds 2-4 (passed @3.9e-3),
// ~3 VALU ops/element instead of ~10.
__device__ __forceinline__ void conv8(const f32x4 va, const f32x4 vb,
                                      bf16x8& ah, bf16x8& al) {
  uint* AH = reinterpret_cast<uint*>(&ah);
  uint* AL = reinterpret_cast<uint*>(&al);
#pragma unroll
  for (int p = 0; p < 4; ++p) {
    float a = (p < 2) ? va[2 * p]     : vb[2 * (p - 2)];
    float b = (p < 2) ? va[2 * p + 1] : vb[2 * (p - 2) + 1];
    __hip_bfloat162 h2 = __float22bfloat162_rn(float2{a, b});
    uint hu;
    __builtin_memcpy(&hu, &h2, 4);
    AH[p] = hu;
    float ra = a - __uint_as_float(hu << 16);            // exact residual (lo elem)
    float rb = b - __uint_as_float(hu & 0xffff0000u);    // exact residual (hi elem)
    __hip_bfloat162 l2 = __float22bfloat162_rn(float2{ra, rb});
    uint lu;
    __builtin_memcpy(&lu, &l2, 4);
    AL[p] = lu;
  }
}

// Pack W_top/W_feat/W_gates^T into MFMA-B-fragment-ordered bf16 hi/lo planes.
__global__ __launch_bounds__(256) void pack_w_kernel(
    const float* __restrict__ Wt, const float* __restrict__ Wf,
    const float* __restrict__ Wg, ushort* __restrict__ Wp) {
  int gid = blockIdx.x * 256 + threadIdx.x;
  if (gid >= 32 * 12 * 64 * 4) return;
  int jp   = gid & 3;
  int t    = gid >> 2;
  int lane = t & 63;
  int t2   = t >> 6;
  int fb   = t2 % 12;
  int ks   = t2 / 12;
  int k0   = ks * 32 + ((lane >> 4) << 3) + jp * 2;
  int f    = fb * 16 + (lane & 15);
  float v0, v1;
  if (f < 64)       { v0 = Wt[k0 * 64 + f];            v1 = Wt[(k0 + 1) * 64 + f]; }
  else if (f < 128) { v0 = Wf[k0 * 64 + f - 64];       v1 = Wf[(k0 + 1) * 64 + f - 64]; }
  else              { v0 = Wg[(f - 128) * D_DIM + k0]; v1 = Wg[(f - 128) * D_DIM + k0 + 1]; }
  ushort h0 = f2bf(v0), h1 = f2bf(v1);
  ushort l0 = f2bf(v0 - bf2f(h0)), l1 = f2bf(v1 - bf2f(h1));
  size_t base = ((size_t)(ks * 12 + fb) * 2) * 512 + lane * 8 + jp * 2;
  *(uint*)(Wp + base)       = (uint)h0 | ((uint)h1 << 16);   // hi plane
  *(uint*)(Wp + base + 512) = (uint)l0 | ((uint)l1 << 16);   // lo plane
}

// 512 blocks x 512 threads (8 waves). Wave (kh,wc) = (wid>>1, wid&1):
//   32 tokens x 96 features x 256 K (split-K x 4). Zero barriers in main loop;
//   B fragments register-double-buffered from L2-resident Wp; A from global x.
//   16 waves/CU = 4 waves/SIMD for latency hiding.
__global__ __launch_bounds__(512, 4) void moe_gate_kernel(
    const float* __restrict__ x, const ushort* __restrict__ Wp,
    const float* __restrict__ b_top, const float* __restrict__ b_feat,
    const float* __restrict__ b_gates, const float* __restrict__ alpha,
    const int* __restrict__ nump, float* __restrict__ out) {
  __shared__ float L[32 * 196 + 192];          // logits [32][196] + biases
  float* bsm = L + 32 * 196;
  const int tid  = threadIdx.x;
  const int lane = tid & 63;
  const int wid  = tid >> 6;        // 0..7
  const int kh   = wid >> 1;        // K-quarter (256 k each)
  const int wc   = wid & 1;         // feature half (96 feats)
  const int tok0 = blockIdx.x * TOKB;

  if (tid < 192)
    bsm[tid] = (tid < 64) ? b_top[tid]
             : (tid < 128) ? b_feat[tid - 64] : b_gates[tid - 128];

  // A sources: 2 token frags; lane reads row tf*16+(lane&15), cols kh*256 + c*32 + (lane>>4)*8
  const float* xp0 = x + (size_t)(tok0 + (lane & 15)) * D_DIM + kh * 256 + ((lane >> 4) << 3);
  const float* xp1 = xp0 + (size_t)16 * D_DIM;
  // B source: fragments fb = wc*6 + fbl, chunks ks = kh*8 + c
  const ushort* wbase = Wp + (size_t)(kh * NCHW) * 12288 + (size_t)(wc * 6) * 1024 + lane * 8;

  f32x4 acc[2][6] = {};
  bf16x8 bAh[6], bAl[6], bBh[6], bBl[6];
  f32x4 xA[4], xB[4];

#define LOADB(BH, BL, c) do {                                        \
    const ushort* wp_ = wbase + (size_t)(c) * 12288;                 \
    _Pragma("unroll")                                                \
    for (int q = 0; q < 6; ++q) {                                    \
      BH[q] = *(const bf16x8*)(wp_ + q * 1024);                      \
      BL[q] = *(const bf16x8*)(wp_ + q * 1024 + 512);                \
    } } while (0)
#define LOADX(XR, c) do {                                            \
    XR[0] = *(const f32x4*)(xp0 + (c) * 32);                         \
    XR[1] = *(const f32x4*)(xp0 + (c) * 32 + 4);                     \
    XR[2] = *(const f32x4*)(xp1 + (c) * 32);                         \
    XR[3] = *(const f32x4*)(xp1 + (c) * 32 + 4); } while (0)
#define COMPUTE(XR, BH, BL) do {                                     \
    bf16x8 ah0, al0, ah1, al1;                                       \
    conv8(XR[0], XR[1], ah0, al0);                                   \
    conv8(XR[2], XR[3], ah1, al1);                                   \
    _Pragma("unroll")                                                \
    for (int q = 0; q < 6; ++q) {                                    \
      acc[0][q] = __builtin_amdgcn_mfma_f32_16x16x32_bf16(ah0, BH[q], acc[0][q], 0, 0, 0); \
      acc[0][q] = __builtin_amdgcn_mfma_f32_16x16x32_bf16(al0, BH[q], acc[0][q], 0, 0, 0); \
      acc[0][q] = __builtin_amdgcn_mfma_f32_16x16x32_bf16(ah0, BL[q], acc[0][q], 0, 0, 0); \
      acc[1][q] = __builtin_amdgcn_mfma_f32_16x16x32_bf16(ah1, BH[q], acc[1][q], 0, 0, 0); \
      acc[1][q] = __builtin_amdgcn_mfma_f32_16x16x32_bf16(al1, BH[q], acc[1][q], 0, 0, 0); \
      acc[1][q] = __builtin_amdgcn_mfma_f32_16x16x32_bf16(ah1, BL[q], acc[1][q], 0, 0, 0); \
    } } while (0)

  // prologue: chunk 0 in flight
  LOADB(bAh, bAl, 0);
  LOADX(xA, 0);
  for (int c = 0; c < NCHW; c += 2) {
    LOADB(bBh, bBl, c + 1);          // prefetch c+1 (covered by COMPUTE c)
    LOADX(xB, c + 1);
    COMPUTE(xA, bAh, bAl);
    if (c + 2 < NCHW) {              // prefetch c+2 (covered by COMPUTE c+1)
      LOADB(bAh, bAl, c + 2);
      LOADX(xA, c + 2);
    }
    COMPUTE(xB, bBh, bBl);
  }
#undef LOADB
#undef LOADX
#undef COMPUTE

  // ---- deterministic split-K combine: 4 barrier-separated phases
  // C/D layout (m89): token = tf*16 + (lane>>4)*4 + r, feat = wc*96 + fbl*16 + (lane&15)
  __syncthreads();                  // bsm visibility; all waves past main loop
  if (kh == 0) {
#pragma unroll
    for (int tf = 0; tf < 2; ++tf)
#pragma unroll
      for (int q = 0; q < 6; ++q) {
        int f = wc * 96 + q * 16 + (lane & 15);
        int t = tf * 16 + ((lane >> 4) << 2);
        float bv = bsm[f];
#pragma unroll
        for (int r = 0; r < 4; ++r)
          L[(t + r) * 196 + f] = acc[tf][q][r] + bv;
      }
  }
  __syncthreads();
#pragma unroll 1
  for (int ph = 1; ph < 4; ++ph) {
    if (kh == ph) {
#pragma unroll
      for (int tf = 0; tf < 2; ++tf)
#pragma unroll
        for (int q = 0; q < 6; ++q) {
          int f = wc * 96 + q * 16 + (lane & 15);
          int t = tf * 16 + ((lane >> 4) << 2);
#pragma unroll
          for (int r = 0; r < 4; ++r)
            L[(t + r) * 196 + f] += acc[tf][q][r];
        }
    }
    __syncthreads();
  }

  // ---- parallel epilogue: 8 lanes per token (t = tid>>3, sub = tid&7),
  // each lane owns features f = sub + 8j, j=0..7
  if (tid < 256) {
    const int t   = tid >> 3;
    const int sub = tid & 7;
    const float* Lr = L + t * 196;
    float tp[8], ftv[8], gtv[8];
#pragma unroll
    for (int j = 0; j < 8; ++j) {
      int f = sub + 8 * j;
      tp[j]  = Lr[f];
      ftv[j] = Lr[64 + f];
      gtv[j] = sigm(Lr[128 + f]);
    }
    // dense branch: softmax(feat) . sigmoid(gates)
    float mf = ftv[0];
#pragma unroll
    for (int j = 1; j < 8; ++j) mf = fmaxf(mf, ftv[j]);
#pragma unroll
    for (int m = 1; m < 8; m <<= 1) mf = fmaxf(mf, __shfl_xor(mf, m, 8));
    float Zf = 0.f, Sf = 0.f;
#pragma unroll
    for (int j = 0; j < 8; ++j) {
      float e = expf(ftv[j] - mf);
      Zf += e;
      Sf = fmaf(gtv[j], e, Sf);
    }
#pragma unroll
    for (int m = 1; m < 8; m <<= 1) {
      Zf += __shfl_xor(Zf, m, 8);
      Sf += __shfl_xor(Sf, m, 8);
    }
    // top-k branch: cooperative argmax, lowest-index tie-break (= lax.top_k)
    int num = *nump;
    num = num < 1 ? 1 : (num > 64 ? 64 : num);
    uint sel8 = 0;
    float m0 = 0.f, Zt = 0.f, St = 0.f;
    for (int k = 0; k < num; ++k) {
      float bv = -3.4e38f; int bj = -1;
#pragma unroll
      for (int j = 0; j < 8; ++j)
        if (!((sel8 >> j) & 1u) && tp[j] > bv) { bv = tp[j]; bj = j; }
      int bf = (bj >= 0) ? (sub + 8 * bj) : (1 << 30);
#pragma unroll
      for (int m = 1; m < 8; m <<= 1) {
        float ov = __shfl_xor(bv, m, 8);
        int   of = __shfl_xor(bf, m, 8);
        if (ov > bv || (ov == bv && of < bf)) { bv = ov; bf = of; }
      }
      if (k == 0) m0 = bv;
      float e = expf(bv - m0);
      Zt += e;
      St = fmaf(sigm(Lr[128 + bf]), e, St);   // uniform addr per group: bcast
      if ((bf & 7) == sub) sel8 |= 1u << (bf >> 3);
    }
    if (sub == 0) {
      float a = sigm(alpha[0]);
      out[tok0 + t] = a * (St / Zt) + (1.f - a) * (Sf / Zf);
    }
  }
}

extern "C" void kernel_launch(void* const* d_in, const int* in_sizes, int n_in,
                              void* d_out, int out_size, void* d_ws, size_t ws_size,
                              hipStream_t stream) {
  const float* x       = (const float*)d_in[0];
  const float* W_top   = (const float*)d_in[1];
  const float* b_top   = (const float*)d_in[2];
  const float* W_feat  = (const float*)d_in[3];
  const float* b_feat  = (const float*)d_in[4];
  const float* W_gates = (const float*)d_in[5];
  const float* b_gates = (const float*)d_in[6];
  const float* alpha   = (const float*)d_in[7];
  const int*   nump    = (const int*)d_in[8];
  float*       out     = (float*)d_out;
  ushort*      Wp      = (ushort*)d_ws;      // 32*12*2*512 ushorts = 768 KB

  int n_tok = in_sizes[0] / D_DIM;           // 16384
  hipLaunchKernelGGL(pack_w_kernel, dim3(384), dim3(256), 0, stream,
                     W_top, W_feat, W_gates, Wp);
  hipLaunchKernelGGL(moe_gate_kernel, dim3(n_tok / TOKB), dim3(512), 0, stream,
                     x, Wp, b_top, b_feat, b_gates, alpha, nump, out);
}

// Round 9
// 162.706 us; speedup vs baseline: 1.4922x; 1.4922x over previous
//
#include <hip/hip_runtime.h>
#include <hip/hip_bf16.h>
#include <math.h>

#define D_DIM 1024
#define TOKB  32            // tokens per block
#define NCH   32            // K-chunks of 32 (full K per wave)
// Wp layout (ushort bf16 bits): [ks 32][fb 12][pl 2][lane 64][j 8]
//   element (lane,j): k = ks*32 + (lane>>4)*8 + j ; f = fb*16 + (lane&15)
//   frag stride = 512 ushorts (1 KB); per-ks stride = 12*2*512 = 12288 ushorts

typedef short  bf16x8 __attribute__((ext_vector_type(8)));
typedef float  f32x4  __attribute__((ext_vector_type(4)));

__device__ __forceinline__ ushort f2bf(float f) {      // RTNE fp32 -> bf16 bits
  uint u = __float_as_uint(f);
  return (ushort)((u + 0x7fffu + ((u >> 16) & 1u)) >> 16);
}
__device__ __forceinline__ float bf2f(ushort h) {
  return __uint_as_float(((uint)h) << 16);
}
__device__ __forceinline__ float sigm(float v) {
  return 1.f / (1.f + expf(-v));
}
// RTNE hi/lo split via HW pack-converter: hi = cvt_pk_bf16(v) (RTNE),
// lo = RTNE(v - hi); residual compensation is exact. Numerics = rounds 2-4.
__device__ __forceinline__ void conv8(const f32x4 va, const f32x4 vb,
                                      bf16x8& ah, bf16x8& al) {
  uint* AH = reinterpret_cast<uint*>(&ah);
  uint* AL = reinterpret_cast<uint*>(&al);
#pragma unroll
  for (int p = 0; p < 4; ++p) {
    float a = (p < 2) ? va[2 * p]     : vb[2 * (p - 2)];
    float b = (p < 2) ? va[2 * p + 1] : vb[2 * (p - 2) + 1];
    __hip_bfloat162 h2 = __float22bfloat162_rn(float2{a, b});
    uint hu;
    __builtin_memcpy(&hu, &h2, 4);
    AH[p] = hu;
    float ra = a - __uint_as_float(hu << 16);
    float rb = b - __uint_as_float(hu & 0xffff0000u);
    __hip_bfloat162 l2 = __float22bfloat162_rn(float2{ra, rb});
    uint lu;
    __builtin_memcpy(&lu, &l2, 4);
    AL[p] = lu;
  }
}

// Pack W_top/W_feat/W_gates^T into MFMA-B-fragment-ordered bf16 hi/lo planes.
__global__ __launch_bounds__(256) void pack_w_kernel(
    const float* __restrict__ Wt, const float* __restrict__ Wf,
    const float* __restrict__ Wg, ushort* __restrict__ Wp) {
  int gid = blockIdx.x * 256 + threadIdx.x;
  if (gid >= 32 * 12 * 64 * 4) return;
  int jp   = gid & 3;
  int t    = gid >> 2;
  int lane = t & 63;
  int t2   = t >> 6;
  int fb   = t2 % 12;
  int ks   = t2 / 12;
  int k0   = ks * 32 + ((lane >> 4) << 3) + jp * 2;
  int f    = fb * 16 + (lane & 15);
  float v0, v1;
  if (f < 64)       { v0 = Wt[k0 * 64 + f];            v1 = Wt[(k0 + 1) * 64 + f]; }
  else if (f < 128) { v0 = Wf[k0 * 64 + f - 64];       v1 = Wf[(k0 + 1) * 64 + f - 64]; }
  else              { v0 = Wg[(f - 128) * D_DIM + k0]; v1 = Wg[(f - 128) * D_DIM + k0 + 1]; }
  ushort h0 = f2bf(v0), h1 = f2bf(v1);
  ushort l0 = f2bf(v0 - bf2f(h0)), l1 = f2bf(v1 - bf2f(h1));
  size_t base = ((size_t)(ks * 12 + fb) * 2) * 512 + lane * 8 + jp * 2;
  *(uint*)(Wp + base)       = (uint)h0 | ((uint)h1 << 16);   // hi plane
  *(uint*)(Wp + base + 512) = (uint)l0 | ((uint)l1 << 16);   // lo plane
}

// 512 blocks x 512 threads (8 waves = tg(2) x wc(4)). Wave: 16 tok x 48 f x
// full K=1024 -> per-wave regs ~95 (acc 12 + B dbuf 48 + x dbuf 16 + addr):
// fits the 128-reg budget of launch_bounds(512,4) with NO spills (round-8
// lesson). 2 blocks/CU = 16 waves/CU = 4 waves/SIMD. No split-K combine:
// each wave writes a disjoint logit region. Zero barriers in main loop.
__global__ __launch_bounds__(512, 4) void moe_gate_kernel(
    const float* __restrict__ x, const ushort* __restrict__ Wp,
    const float* __restrict__ b_top, const float* __restrict__ b_feat,
    const float* __restrict__ b_gates, const float* __restrict__ alpha,
    const int* __restrict__ nump, float* __restrict__ out) {
  __shared__ float L[32 * 196 + 192];          // logits [32][196] + biases
  float* bsm = L + 32 * 196;
  const int tid  = threadIdx.x;
  const int lane = tid & 63;
  const int wid  = tid >> 6;        // 0..7
  const int tg   = wid >> 2;        // token half (16 tokens)
  const int wc   = wid & 3;         // feature quarter (48 feats)
  const int tok0 = blockIdx.x * TOKB;

  if (tid < 192)
    bsm[tid] = (tid < 64) ? b_top[tid]
             : (tid < 128) ? b_feat[tid - 64] : b_gates[tid - 128];

  // A source: lane reads x[tok0 + tg*16 + (lane&15)][c*32 + (lane>>4)*8 + 0..7]
  const float* xp = x + (size_t)(tok0 + tg * 16 + (lane & 15)) * D_DIM
                      + ((lane >> 4) << 3);
  // B source: fragments fb = wc*3 + q, all 32 chunks
  const ushort* wbase = Wp + (size_t)(wc * 3) * 1024 + lane * 8;

  f32x4 acc[3] = {};
  bf16x8 bAh[3], bAl[3], bBh[3], bBl[3];
  f32x4 xA[2], xB[2];

#define LOADB(BH, BL, c) do {                                        \
    const ushort* wp_ = wbase + (size_t)(c) * 12288;                 \
    _Pragma("unroll")                                                \
    for (int q = 0; q < 3; ++q) {                                    \
      BH[q] = *(const bf16x8*)(wp_ + q * 1024);                      \
      BL[q] = *(const bf16x8*)(wp_ + q * 1024 + 512);                \
    } } while (0)
#define LOADX(XR, c) do {                                            \
    XR[0] = *(const f32x4*)(xp + (c) * 32);                          \
    XR[1] = *(const f32x4*)(xp + (c) * 32 + 4); } while (0)
#define COMPUTE(XR, BH, BL) do {                                     \
    bf16x8 ah, al;                                                   \
    conv8(XR[0], XR[1], ah, al);                                     \
    _Pragma("unroll")                                                \
    for (int q = 0; q < 3; ++q) {                                    \
      acc[q] = __builtin_amdgcn_mfma_f32_16x16x32_bf16(ah, BH[q], acc[q], 0, 0, 0); \
      acc[q] = __builtin_amdgcn_mfma_f32_16x16x32_bf16(al, BH[q], acc[q], 0, 0, 0); \
      acc[q] = __builtin_amdgcn_mfma_f32_16x16x32_bf16(ah, BL[q], acc[q], 0, 0, 0); \
    } } while (0)

  // prologue: chunk 0 in flight
  LOADB(bAh, bAl, 0);
  LOADX(xA, 0);
  for (int c = 0; c < NCH; c += 2) {
    LOADB(bBh, bBl, c + 1);          // prefetch c+1 (covered by COMPUTE c)
    LOADX(xB, c + 1);
    COMPUTE(xA, bAh, bAl);
    if (c + 2 < NCH) {               // prefetch c+2 (covered by COMPUTE c+1)
      LOADB(bAh, bAl, c + 2);
      LOADX(xA, c + 2);
    }
    COMPUTE(xB, bBh, bBl);
  }
#undef LOADB
#undef LOADX
#undef COMPUTE

  // ---- write logits (+bias): waves own disjoint (token, feat) regions.
  // C/D layout (m89): token = tg*16 + (lane>>4)*4 + r, feat = wc*48 + q*16 + (lane&15)
  __syncthreads();                  // bsm visibility; all waves past main loop
#pragma unroll
  for (int q = 0; q < 3; ++q) {
    int f = wc * 48 + q * 16 + (lane & 15);
    int t = tg * 16 + ((lane >> 4) << 2);
    float bv = bsm[f];
#pragma unroll
    for (int r = 0; r < 4; ++r)
      L[(t + r) * 196 + f] = acc[q][r] + bv;
  }
  __syncthreads();

  // ---- parallel epilogue: 8 lanes per token (t = tid>>3, sub = tid&7),
  // each lane owns features f = sub + 8j, j=0..7
  if (tid < 256) {
    const int t   = tid >> 3;
    const int sub = tid & 7;
    const float* Lr = L + t * 196;
    float tp[8], ftv[8], gtv[8];
#pragma unroll
    for (int j = 0; j < 8; ++j) {
      int f = sub + 8 * j;
      tp[j]  = Lr[f];
      ftv[j] = Lr[64 + f];
      gtv[j] = sigm(Lr[128 + f]);
    }
    // dense branch: softmax(feat) . sigmoid(gates)
    float mf = ftv[0];
#pragma unroll
    for (int j = 1; j < 8; ++j) mf = fmaxf(mf, ftv[j]);
#pragma unroll
    for (int m = 1; m < 8; m <<= 1) mf = fmaxf(mf, __shfl_xor(mf, m, 8));
    float Zf = 0.f, Sf = 0.f;
#pragma unroll
    for (int j = 0; j < 8; ++j) {
      float e = expf(ftv[j] - mf);
      Zf += e;
      Sf = fmaf(gtv[j], e, Sf);
    }
#pragma unroll
    for (int m = 1; m < 8; m <<= 1) {
      Zf += __shfl_xor(Zf, m, 8);
      Sf += __shfl_xor(Sf, m, 8);
    }
    // top-k branch: cooperative argmax, lowest-index tie-break (= lax.top_k)
    int num = *nump;
    num = num < 1 ? 1 : (num > 64 ? 64 : num);
    uint sel8 = 0;
    float m0 = 0.f, Zt = 0.f, St = 0.f;
    for (int k = 0; k < num; ++k) {
      float bv = -3.4e38f; int bj = -1;
#pragma unroll
      for (int j = 0; j < 8; ++j)
        if (!((sel8 >> j) & 1u) && tp[j] > bv) { bv = tp[j]; bj = j; }
      int bf = (bj >= 0) ? (sub + 8 * bj) : (1 << 30);
#pragma unroll
      for (int m = 1; m < 8; m <<= 1) {
        float ov = __shfl_xor(bv, m, 8);
        int   of = __shfl_xor(bf, m, 8);
        if (ov > bv || (ov == bv && of < bf)) { bv = ov; bf = of; }
      }
      if (k == 0) m0 = bv;
      float e = expf(bv - m0);
      Zt += e;
      St = fmaf(sigm(Lr[128 + bf]), e, St);   // uniform addr per group: bcast
      if ((bf & 7) == sub) sel8 |= 1u << (bf >> 3);
    }
    if (sub == 0) {
      float a = sigm(alpha[0]);
      out[tok0 + t] = a * (St / Zt) + (1.f - a) * (Sf / Zf);
    }
  }
}

extern "C" void kernel_launch(void* const* d_in, const int* in_sizes, int n_in,
                              void* d_out, int out_size, void* d_ws, size_t ws_size,
                              hipStream_t stream) {
  const float* x       = (const float*)d_in[0];
  const float* W_top   = (const float*)d_in[1];
  const float* b_top   = (const float*)d_in[2];
  const float* W_feat  = (const float*)d_in[3];
  const float* b_feat  = (const float*)d_in[4];
  const float* W_gates = (const float*)d_in[5];
  const float* b_gates = (const float*)d_in[6];
  const float* alpha   = (const float*)d_in[7];
  const int*   nump    = (const int*)d_in[8];
  float*       out     = (float*)d_out;
  ushort*      Wp      = (ushort*)d_ws;      // 32*12*2*512 ushorts = 768 KB

  int n_tok = in_sizes[0] / D_DIM;           // 16384
  hipLaunchKernelGGL(pack_w_kernel, dim3(384), dim3(256), 0, stream,
                     W_top, W_feat, W_gates, Wp);
  hipLaunchKernelGGL(moe_gate_kernel, dim3(n_tok / TOKB), dim3(512), 0, stream,
                     x, Wp, b_top, b_feat, b_gates, alpha, nump, out);
}

// Round 10
// 151.228 us; speedup vs baseline: 1.6055x; 1.0759x over previous
//
#include <hip/hip_runtime.h>
#include <hip/hip_bf16.h>
#include <math.h>

#define D_DIM 1024
#define TOKB  32            // tokens per block
#define NCH   32            // K-chunks of 32 (full K per wave)
// Wp layout (ushort bf16 bits): [ks 32][fb 12][pl 2][lane 64][j 8]
//   element (lane,j): k = ks*32 + (lane>>4)*8 + j ; f = fb*16 + (lane&15)
//   per-chunk block = 24576 B, contiguous & lane-ordered == gload_lds layout.

typedef short  bf16x8 __attribute__((ext_vector_type(8)));
typedef float  f32x4  __attribute__((ext_vector_type(4)));

__device__ __forceinline__ ushort f2bf(float f) {      // RTNE fp32 -> bf16 bits
  uint u = __float_as_uint(f);
  return (ushort)((u + 0x7fffu + ((u >> 16) & 1u)) >> 16);
}
__device__ __forceinline__ float bf2f(ushort h) {
  return __uint_as_float(((uint)h) << 16);
}
__device__ __forceinline__ float sigm(float v) {
  return 1.f / (1.f + expf(-v));
}
__device__ __forceinline__ void gload16(const void* g, void* l) {
  __builtin_amdgcn_global_load_lds((const __attribute__((address_space(1))) void*)g,
                                   (__attribute__((address_space(3))) void*)l, 16, 0, 0);
}
// RTNE hi/lo split via HW pack-converter (numerics = rounds 2-4/8/9, passed).
__device__ __forceinline__ void conv8(const f32x4 va, const f32x4 vb,
                                      bf16x8& ah, bf16x8& al) {
  uint* AH = reinterpret_cast<uint*>(&ah);
  uint* AL = reinterpret_cast<uint*>(&al);
#pragma unroll
  for (int p = 0; p < 4; ++p) {
    float a = (p < 2) ? va[2 * p]     : vb[2 * (p - 2)];
    float b = (p < 2) ? va[2 * p + 1] : vb[2 * (p - 2) + 1];
    __hip_bfloat162 h2 = __float22bfloat162_rn(float2{a, b});
    uint hu;
    __builtin_memcpy(&hu, &h2, 4);
    AH[p] = hu;
    float ra = a - __uint_as_float(hu << 16);
    float rb = b - __uint_as_float(hu & 0xffff0000u);
    __hip_bfloat162 l2 = __float22bfloat162_rn(float2{ra, rb});
    uint lu;
    __builtin_memcpy(&lu, &l2, 4);
    AL[p] = lu;
  }
}

// Pack W_top/W_feat/W_gates^T into MFMA-B-fragment-ordered bf16 hi/lo planes.
__global__ __launch_bounds__(256) void pack_w_kernel(
    const float* __restrict__ Wt, const float* __restrict__ Wf,
    const float* __restrict__ Wg, ushort* __restrict__ Wp) {
  int gid = blockIdx.x * 256 + threadIdx.x;
  if (gid >= 32 * 12 * 64 * 4) return;
  int jp   = gid & 3;
  int t    = gid >> 2;
  int lane = t & 63;
  int t2   = t >> 6;
  int fb   = t2 % 12;
  int ks   = t2 / 12;
  int k0   = ks * 32 + ((lane >> 4) << 3) + jp * 2;
  int f    = fb * 16 + (lane & 15);
  float v0, v1;
  if (f < 64)       { v0 = Wt[k0 * 64 + f];            v1 = Wt[(k0 + 1) * 64 + f]; }
  else if (f < 128) { v0 = Wf[k0 * 64 + f - 64];       v1 = Wf[(k0 + 1) * 64 + f - 64]; }
  else              { v0 = Wg[(f - 128) * D_DIM + k0]; v1 = Wg[(f - 128) * D_DIM + k0 + 1]; }
  ushort h0 = f2bf(v0), h1 = f2bf(v1);
  ushort l0 = f2bf(v0 - bf2f(h0)), l1 = f2bf(v1 - bf2f(h1));
  size_t base = ((size_t)(ks * 12 + fb) * 2) * 512 + lane * 8 + jp * 2;
  *(uint*)(Wp + base)       = (uint)h0 | ((uint)h1 << 16);   // hi plane
  *(uint*)(Wp + base + 512) = (uint)l0 | ((uint)l1 << 16);   // lo plane
}

// 512 blocks x 512 threads (8 waves = tg(2) x wc(4)); wave: 16 tok x 48 f x
// full K. W double-buffered in LDS via global_load_lds (2x24 KB); counted
// vmcnt(2) keeps the x-prefetch in flight across raw s_barriers (T3/T4).
__global__ __launch_bounds__(512, 4) void moe_gate_kernel(
    const float* __restrict__ x, const ushort* __restrict__ Wp,
    const float* __restrict__ b_top, const float* __restrict__ b_feat,
    const float* __restrict__ b_gates, const float* __restrict__ alpha,
    const int* __restrict__ nump, float* __restrict__ out) {
  __shared__ __align__(16) char smem[49920];
  char* buf0 = smem;                    // W chunk buffers, 24576 B each
  char* buf1 = smem + 24576;
  float* bsm = (float*)(smem + 49152);  // 192 biases
  float* L   = (float*)smem;            // epilogue overlay [32][196]

  const int tid  = threadIdx.x;
  const int lane = tid & 63;
  const int wid  = tid >> 6;        // 0..7
  const int tg   = wid >> 2;        // token half (16 tokens)
  const int wc   = wid & 3;         // feature quarter (48 feats)
  const int tok0 = blockIdx.x * TOKB;

  if (tid < 192)                    // bias stage (drained by prologue wait)
    bsm[tid] = (tid < 64) ? b_top[tid]
             : (tid < 128) ? b_feat[tid - 64] : b_gates[tid - 128];

  // A source: lane reads x[tok0 + tg*16 + (lane&15)][c*32 + (lane>>4)*8 + 0..7]
  const float* xp = x + (size_t)(tok0 + tg * 16 + (lane & 15)) * D_DIM
                      + ((lane >> 4) << 3);
  // staging: thread covers bytes {stgu + lane*16 + p*8192}, p=0..2 (bijective 24 KB)
  const int stgu = wid * 1024;                 // wave-uniform LDS offset
  const char* wsrc = (const char*)Wp + stgu + lane * 16;
  // fragment read offset: fb = wc*3+q -> (fb*2+pl)*1024 + lane*16
  const int fro = wc * 6144 + lane * 16;

  f32x4 acc[3] = {};
  f32x4 xA0, xA1, xB0, xB1;

#define STAGE(dbuf, c) do {                                          \
    const char* s_ = wsrc + (size_t)(c) * 24576;                     \
    char* d_ = (dbuf) + stgu;                                        \
    gload16(s_, d_);                                                 \
    gload16(s_ + 8192,  d_ + 8192);                                  \
    gload16(s_ + 16384, d_ + 16384); } while (0)
#define COMPUTE(cbuf, X0, X1) do {                                   \
    const char* bp_ = (cbuf) + fro;                                  \
    bf16x8 bh0 = *(const bf16x8*)(bp_);                              \
    bf16x8 bl0 = *(const bf16x8*)(bp_ + 1024);                       \
    bf16x8 bh1 = *(const bf16x8*)(bp_ + 2048);                       \
    bf16x8 bl1 = *(const bf16x8*)(bp_ + 3072);                       \
    bf16x8 bh2 = *(const bf16x8*)(bp_ + 4096);                       \
    bf16x8 bl2 = *(const bf16x8*)(bp_ + 5120);                       \
    bf16x8 ah, al;                                                   \
    conv8(X0, X1, ah, al);                                           \
    acc[0] = __builtin_amdgcn_mfma_f32_16x16x32_bf16(ah, bh0, acc[0], 0, 0, 0); \
    acc[0] = __builtin_amdgcn_mfma_f32_16x16x32_bf16(al, bh0, acc[0], 0, 0, 0); \
    acc[0] = __builtin_amdgcn_mfma_f32_16x16x32_bf16(ah, bl0, acc[0], 0, 0, 0); \
    acc[1] = __builtin_amdgcn_mfma_f32_16x16x32_bf16(ah, bh1, acc[1], 0, 0, 0); \
    acc[1] = __builtin_amdgcn_mfma_f32_16x16x32_bf16(al, bh1, acc[1], 0, 0, 0); \
    acc[1] = __builtin_amdgcn_mfma_f32_16x16x32_bf16(ah, bl1, acc[1], 0, 0, 0); \
    acc[2] = __builtin_amdgcn_mfma_f32_16x16x32_bf16(ah, bh2, acc[2], 0, 0, 0); \
    acc[2] = __builtin_amdgcn_mfma_f32_16x16x32_bf16(al, bh2, acc[2], 0, 0, 0); \
    acc[2] = __builtin_amdgcn_mfma_f32_16x16x32_bf16(ah, bl2, acc[2], 0, 0, 0); \
  } while (0)
#define WAITV(n) do {                                                \
    asm volatile("s_waitcnt vmcnt(" #n ")" ::: "memory");            \
    __builtin_amdgcn_sched_barrier(0); } while (0)
#define BAR() do {                                                   \
    __builtin_amdgcn_s_barrier();                                    \
    __builtin_amdgcn_sched_barrier(0); } while (0)

  // ---- prologue: W(0) -> buf0; x(0), x(1) -> regs
  STAGE(buf0, 0);
  xA0 = *(const f32x4*)(xp);       xA1 = *(const f32x4*)(xp + 4);
  xB0 = *(const f32x4*)(xp + 32);  xB1 = *(const f32x4*)(xp + 36);
  WAITV(4);                        // drain W(0) (+bias); keep x(0),x(1)
  BAR();

  // ---- main loop: pairs (t, t+1), t = 0..28; peel (30, 31)
  for (int t = 0; t < 30; t += 2) {
    // body A: compute even t from buf0; stage t+1 -> buf1; load x(t+2)
    STAGE(buf1, t + 1);
    f32x4 n0 = *(const f32x4*)(xp + (t + 2) * 32);
    f32x4 n1 = *(const f32x4*)(xp + (t + 2) * 32 + 4);
    COMPUTE(buf0, xA0, xA1);
    xA0 = n0; xA1 = n1;
    WAITV(2);                      // drain W(t+1); keep x(t+2)
    BAR();
    // body B: compute odd t+1 from buf1; stage t+2 -> buf0; load x(t+3)
    STAGE(buf0, t + 2);
    f32x4 m0 = *(const f32x4*)(xp + (t + 3) * 32);
    f32x4 m1 = *(const f32x4*)(xp + (t + 3) * 32 + 4);
    COMPUTE(buf1, xB0, xB1);
    xB0 = m0; xB1 = m1;
    WAITV(2);                      // drain W(t+2); keep x(t+3)
    BAR();
  }
  // peeled tail: chunks 30, 31
  STAGE(buf1, 31);
  COMPUTE(buf0, xA0, xA1);         // chunk 30
  WAITV(0);
  BAR();
  COMPUTE(buf1, xB0, xB1);         // chunk 31
#undef STAGE
#undef COMPUTE
#undef WAITV
#undef BAR

  __syncthreads();                 // full drain; buffers reusable as L overlay
  // ---- write logits (+bias): disjoint regions per wave.
  // C/D layout (m89): token = tg*16 + (lane>>4)*4 + r, feat = wc*48 + q*16 + (lane&15)
#pragma unroll
  for (int q = 0; q < 3; ++q) {
    int f = wc * 48 + q * 16 + (lane & 15);
    int t = tg * 16 + ((lane >> 4) << 2);
    float bv = bsm[f];
#pragma unroll
    for (int r = 0; r < 4; ++r)
      L[(t + r) * 196 + f] = acc[q][r] + bv;
  }
  __syncthreads();

  // ---- parallel epilogue: 8 lanes per token (t = tid>>3, sub = tid&7)
  if (tid < 256) {
    const int t   = tid >> 3;
    const int sub = tid & 7;
    const float* Lr = L + t * 196;
    float tp[8], ftv[8], gtv[8];
#pragma unroll
    for (int j = 0; j < 8; ++j) {
      int f = sub + 8 * j;
      tp[j]  = Lr[f];
      ftv[j] = Lr[64 + f];
      gtv[j] = sigm(Lr[128 + f]);
    }
    // dense branch: softmax(feat) . sigmoid(gates)
    float mf = ftv[0];
#pragma unroll
    for (int j = 1; j < 8; ++j) mf = fmaxf(mf, ftv[j]);
#pragma unroll
    for (int m = 1; m < 8; m <<= 1) mf = fmaxf(mf, __shfl_xor(mf, m, 8));
    float Zf = 0.f, Sf = 0.f;
#pragma unroll
    for (int j = 0; j < 8; ++j) {
      float e = expf(ftv[j] - mf);
      Zf += e;
      Sf = fmaf(gtv[j], e, Sf);
    }
#pragma unroll
    for (int m = 1; m < 8; m <<= 1) {
      Zf += __shfl_xor(Zf, m, 8);
      Sf += __shfl_xor(Sf, m, 8);
    }
    // top-k branch: cooperative argmax, lowest-index tie-break (= lax.top_k)
    int num = *nump;
    num = num < 1 ? 1 : (num > 64 ? 64 : num);
    uint sel8 = 0;
    float m0 = 0.f, Zt = 0.f, St = 0.f;
    for (int k = 0; k < num; ++k) {
      float bv = -3.4e38f; int bj = -1;
#pragma unroll
      for (int j = 0; j < 8; ++j)
        if (!((sel8 >> j) & 1u) && tp[j] > bv) { bv = tp[j]; bj = j; }
      int bf = (bj >= 0) ? (sub + 8 * bj) : (1 << 30);
#pragma unroll
      for (int m = 1; m < 8; m <<= 1) {
        float ov = __shfl_xor(bv, m, 8);
        int   of = __shfl_xor(bf, m, 8);
        if (ov > bv || (ov == bv && of < bf)) { bv = ov; bf = of; }
      }
      if (k == 0) m0 = bv;
      float e = expf(bv - m0);
      Zt += e;
      St = fmaf(sigm(Lr[128 + bf]), e, St);   // uniform addr per group: bcast
      if ((bf & 7) == sub) sel8 |= 1u << (bf >> 3);
    }
    if (sub == 0) {
      float a = sigm(alpha[0]);
      out[tok0 + t] = a * (St / Zt) + (1.f - a) * (Sf / Zf);
    }
  }
}

extern "C" void kernel_launch(void* const* d_in, const int* in_sizes, int n_in,
                              void* d_out, int out_size, void* d_ws, size_t ws_size,
                              hipStream_t stream) {
  const float* x       = (const float*)d_in[0];
  const float* W_top   = (const float*)d_in[1];
  const float* b_top   = (const float*)d_in[2];
  const float* W_feat  = (const float*)d_in[3];
  const float* b_feat  = (const float*)d_in[4];
  const float* W_gates = (const float*)d_in[5];
  const float* b_gates = (const float*)d_in[6];
  const float* alpha   = (const float*)d_in[7];
  const int*   nump    = (const int*)d_in[8];
  float*       out     = (float*)d_out;
  ushort*      Wp      = (ushort*)d_ws;      // 32 chunks x 24576 B = 768 KB

  int n_tok = in_sizes[0] / D_DIM;           // 16384
  hipLaunchKernelGGL(pack_w_kernel, dim3(384), dim3(256), 0, stream,
                     W_top, W_feat, W_gates, Wp);
  hipLaunchKernelGGL(moe_gate_kernel, dim3(n_tok / TOKB), dim3(512), 0, stream,
                     x, Wp, b_top, b_feat, b_gates, alpha, nump, out);
}